// Round 2
// baseline (279.556 us; speedup 1.0000x reference)
//
#include <hip/hip_runtime.h>

#define BGR 8
#define VG  20000
#define NK  128
#define ND  128

typedef float f32x4 __attribute__((ext_vector_type(4)));
typedef short bf16x8 __attribute__((ext_vector_type(8)));

// fp32 -> bf16 bits, round-to-nearest-even
__device__ __forceinline__ unsigned short bf16r(float f) {
    union { float f; unsigned u; } c; c.f = f;
    return (unsigned short)((c.u + 0x7FFFu + ((c.u >> 16) & 1u)) >> 16);
}
__device__ __forceinline__ unsigned pack2(float a, float b) {
    return (unsigned)bf16r(a) | ((unsigned)bf16r(b) << 16);
}

// ---------------------------------------------------------------------------
// Kernel 1: x_spec[g][k][d] += sum_v E[v,k]*m[v]*x[v,d]  (per 160-v chunk)
// Transpose-stage 32-v slabs into LDS (layout [chan][v], stride 40 shorts).
// Staging task = 2v x 4c per thread-iter: float4 global loads, paired-bf16
// 4B LDS stores -> bank = (16*cq + vp) mod 32 = 2-way (free).
// ---------------------------------------------------------------------------
#define VC 160
#define S1 40

__global__ __launch_bounds__(256) void k_spec(const float* __restrict__ x,
                                              const float* __restrict__ mass,
                                              const float* __restrict__ evecs,
                                              float* __restrict__ xs) {
    const int g  = blockIdx.y;
    const int v0 = blockIdx.x * VC;

    const float* xg = x     + (size_t)g * VG * ND;
    const float* eg = evecs + (size_t)g * VG * NK;
    const float* mg = mass  + (size_t)g * VG;

    __shared__ short At[NK * S1];  // [k_eig][v]
    __shared__ short Bt[ND * S1];  // [d][v]

    const int tid = threadIdx.x;
    const int l   = tid & 63;
    const int w   = tid >> 6;
    const int lo  = l & 15, hi = l >> 4;
    const int r0  = (w & 1) * 64, c0 = (w >> 1) * 64;

    f32x4 acc[4][4] = {};

#pragma unroll 1
    for (int r = 0; r < VC / 32; ++r) {
        const int vb = v0 + r * 32;
        // stage 32 rows x 128 chans of both matrices, transposed, fp32->bf16
#pragma unroll
        for (int it = 0; it < 2; ++it) {
            const int id = it * 256 + tid;      // 0..511
            const int vp = id & 15;             // v-pair index
            const int cq = id >> 4;             // 0..31, 4-chan group
            const int v  = vb + 2 * vp;
            const float2 mm = *(const float2*)(mg + v);
            const f32x4 xa = *(const f32x4*)(xg + (size_t)v * ND + 4 * cq);
            const f32x4 xb = *(const f32x4*)(xg + (size_t)(v + 1) * ND + 4 * cq);
            const f32x4 ea = *(const f32x4*)(eg + (size_t)v * NK + 4 * cq);
            const f32x4 eb = *(const f32x4*)(eg + (size_t)(v + 1) * NK + 4 * cq);
#pragma unroll
            for (int i = 0; i < 4; ++i) {
                const int c = 4 * cq + i;
                *(unsigned*)(Bt + c * S1 + 2 * vp) = pack2(xa[i] * mm.x, xb[i] * mm.y);
                *(unsigned*)(At + c * S1 + 2 * vp) = pack2(ea[i], eb[i]);
            }
        }
        __syncthreads();

        bf16x8 af[4], bfv[4];
#pragma unroll
        for (int i = 0; i < 4; ++i)
            af[i] = *(const bf16x8*)(At + (r0 + 16 * i + lo) * S1 + hi * 8);
#pragma unroll
        for (int j = 0; j < 4; ++j)
            bfv[j] = *(const bf16x8*)(Bt + (c0 + 16 * j + lo) * S1 + hi * 8);
#pragma unroll
        for (int i = 0; i < 4; ++i)
#pragma unroll
            for (int j = 0; j < 4; ++j)
                acc[i][j] = __builtin_amdgcn_mfma_f32_16x16x32_bf16(af[i], bfv[j], acc[i][j], 0, 0, 0);
        __syncthreads();
    }

    float* og = xs + (size_t)g * NK * ND;
#pragma unroll
    for (int i = 0; i < 4; ++i)
#pragma unroll
        for (int j = 0; j < 4; ++j)
#pragma unroll
            for (int t = 0; t < 4; ++t) {
                const int kk = r0 + 16 * i + hi * 4 + t;   // C row = (lane>>4)*4+reg
                const int dd = c0 + 16 * j + lo;           // C col = lane&15
                atomicAdd(og + kk * ND + dd, acc[i][j][t]);
            }
}

// ---------------------------------------------------------------------------
// Kernel 2: Yt[g][d][k] = bf16( exp(-evals[g,k]*max(t[d],1e-8)) * xs[g][k][d] )
// ---------------------------------------------------------------------------
__global__ __launch_bounds__(256) void k_coef(const float* __restrict__ xs,
                                              const float* __restrict__ evals,
                                              const float* __restrict__ dt,
                                              unsigned short* __restrict__ Yt) {
    const int gid = blockIdx.x * 256 + threadIdx.x;   // 0 .. 8*128*128-1
    const int g = gid >> 14;
    const int d = (gid >> 7) & 127;
    const int k = gid & 127;
    const float t   = fmaxf(dt[d], 1e-8f);
    const float lam = evals[g * NK + k];
    const float v   = xs[(size_t)g * NK * ND + k * ND + d];
    Yt[gid] = bf16r(__expf(-lam * t) * v);
}

// ---------------------------------------------------------------------------
// Kernel 3: out[v,d] = sum_k E[v,k] * Yt[g][d][k]
// A tile staged in LDS (stride 136 breaks the 16-way read conflict of 128);
// B fragments read straight from global (Yt is 256KB total, L2-resident,
// 16B/lane fully-coalesced loads).
// ---------------------------------------------------------------------------
#define S2 136  // 128+8 shorts: 272B rows, 16B-aligned, bank-spread fragment reads

__global__ __launch_bounds__(256) void k_out(const float* __restrict__ evecs,
                                             const short* __restrict__ Yt,
                                             float* __restrict__ out) {
    const int g     = blockIdx.y;
    const int chunk = blockIdx.x;               // 157 chunks: 156 full + one 32-row tail
    const int v0    = chunk * 128;
    const int rows  = (VG - v0 < 128) ? (VG - v0) : 128;

    const float* eg = evecs + (size_t)g * VG * NK;
    float*       og = out   + (size_t)g * VG * ND;
    const short* yg = Yt    + (size_t)g * ND * NK;

    __shared__ short As[128 * S2];  // E tile [v][k] bf16, 34KB

    const int tid = threadIdx.x;
#pragma unroll
    for (int it = 0; it < 16; ++it) {
        const int id = it * 256 + tid;           // 0..4095 float4-tasks
        const int v  = id >> 5;                  // 0..127
        const int c4 = id & 31;                  // 32 x 4-elem groups
        const int vc = v < rows ? v : rows - 1;  // clamp tail OOB reads
        const f32x4 e4 = *(const f32x4*)(eg + (size_t)(v0 + vc) * NK + 4 * c4);
        short4 p;
        p.x = (short)bf16r(e4.x); p.y = (short)bf16r(e4.y);
        p.z = (short)bf16r(e4.z); p.w = (short)bf16r(e4.w);
        *(short4*)(As + v * S2 + 4 * c4) = p;
    }
    __syncthreads();

    const int l  = tid & 63;
    const int w  = tid >> 6;
    const int lo = l & 15, hi = l >> 4;
    const int r0 = (w & 1) * 64, c0 = (w >> 1) * 64;

    f32x4 acc[4][4] = {};
#pragma unroll
    for (int ks = 0; ks < 4; ++ks) {
        const int k0 = ks * 32;
        bf16x8 af[4], bfv[4];
#pragma unroll
        for (int j = 0; j < 4; ++j)
            bfv[j] = *(const bf16x8*)(yg + (size_t)(c0 + 16 * j + lo) * NK + k0 + hi * 8);
#pragma unroll
        for (int i = 0; i < 4; ++i)
            af[i] = *(const bf16x8*)(As + (r0 + 16 * i + lo) * S2 + k0 + hi * 8);
#pragma unroll
        for (int i = 0; i < 4; ++i)
#pragma unroll
            for (int j = 0; j < 4; ++j)
                acc[i][j] = __builtin_amdgcn_mfma_f32_16x16x32_bf16(af[i], bfv[j], acc[i][j], 0, 0, 0);
    }

#pragma unroll
    for (int i = 0; i < 4; ++i)
#pragma unroll
        for (int j = 0; j < 4; ++j)
#pragma unroll
            for (int t = 0; t < 4; ++t) {
                const int vv = r0 + 16 * i + hi * 4 + t;
                if (vv < rows)
                    og[(size_t)(v0 + vv) * ND + c0 + 16 * j + lo] = acc[i][j][t];
            }
}

extern "C" void kernel_launch(void* const* d_in, const int* in_sizes, int n_in,
                              void* d_out, int out_size, void* d_ws, size_t ws_size,
                              hipStream_t stream) {
    const float* x     = (const float*)d_in[0];
    const float* mass  = (const float*)d_in[1];
    const float* evals = (const float*)d_in[2];
    const float* evecs = (const float*)d_in[3];
    const float* dt    = (const float*)d_in[4];
    float* out = (float*)d_out;

    float*          xs = (float*)d_ws;                                      // 8*128*128 fp32 = 512KB
    unsigned short* Yt = (unsigned short*)((char*)d_ws + (size_t)BGR * NK * ND * 4);

    hipMemsetAsync(d_ws, 0, (size_t)BGR * NK * ND * sizeof(float), stream);

    k_spec<<<dim3(VG / VC, BGR), 256, 0, stream>>>(x, mass, evecs, xs);
    k_coef<<<(BGR * NK * ND) / 256, 256, 0, stream>>>(xs, evals, dt, Yt);
    k_out<<<dim3((VG + 127) / 128, BGR), 256, 0, stream>>>(evecs, (const short*)Yt, out);
}

// Round 3
// 263.806 us; speedup vs baseline: 1.0597x; 1.0597x over previous
//
#include <hip/hip_runtime.h>

#define BGR 8
#define VG  20000
#define NK  128
#define ND  128
#define VC  320
#define NB  ((VG + VC - 1) / VC)   // 63 chunks per graph (62 full + one 160-v tail)

typedef float f32x4 __attribute__((ext_vector_type(4)));
typedef short bf16x8 __attribute__((ext_vector_type(8)));

// fp32 -> bf16 bits, round-to-nearest-even
__device__ __forceinline__ unsigned short bf16r(float f) {
    union { float f; unsigned u; } c; c.f = f;
    return (unsigned short)((c.u + 0x7FFFu + ((c.u >> 16) & 1u)) >> 16);
}
__device__ __forceinline__ unsigned pack2(float a, float b) {
    return (unsigned)bf16r(a) | ((unsigned)bf16r(b) << 16);
}

// ---------------------------------------------------------------------------
// Kernel 1: P[g][b][k][d] = sum_{v in chunk b} E[v,k]*m[v]*x[v,d]
// Barrier-free, no LDS: MFMA fragments gathered straight from global.
// A-frag lane (m=k_e=lane&15 [+16i+r0], k=v=(lane>>4)*8+jj): per instr the
// wave reads 4 rows x 64B contiguous segments -> coalesced. All ~72 dword
// loads of a round are bulk-issued into registers, so each wave keeps the
// full round's traffic in flight (latency-tolerant without barriers).
// ---------------------------------------------------------------------------
template<int ATOMIC>
__global__ __launch_bounds__(256, 2) void k_spec(const float* __restrict__ x,
                                                 const float* __restrict__ mass,
                                                 const float* __restrict__ evecs,
                                                 float* __restrict__ P) {
    const int g  = blockIdx.y;
    const int b  = blockIdx.x;
    const int v0 = b * VC;
    const int rounds = ((VG - v0 < VC) ? (VG - v0) : VC) >> 5;

    const float* xg = x     + (size_t)g * VG * ND;
    const float* eg = evecs + (size_t)g * VG * NK;
    const float* mg = mass  + (size_t)g * VG;

    const int tid = threadIdx.x;
    const int l  = tid & 63, w = tid >> 6;
    const int lo = l & 15, hi = l >> 4;
    const int r0 = (w & 1) * 64, c0 = (w >> 1) * 64;

    f32x4 acc[4][4] = {};

#pragma unroll 1
    for (int r = 0; r < rounds; ++r) {
        const int vb = v0 + r * 32 + hi * 8;   // this lane's 8-v slab base

        float mj[8], ta[4][8], tb[4][8];
#pragma unroll
        for (int jj = 0; jj < 8; ++jj) mj[jj] = mg[vb + jj];
#pragma unroll
        for (int i = 0; i < 4; ++i)
#pragma unroll
            for (int jj = 0; jj < 8; ++jj)
                ta[i][jj] = eg[(size_t)(vb + jj) * NK + r0 + 16 * i + lo];
#pragma unroll
        for (int j = 0; j < 4; ++j)
#pragma unroll
            for (int jj = 0; jj < 8; ++jj)
                tb[j][jj] = xg[(size_t)(vb + jj) * ND + c0 + 16 * j + lo];

        bf16x8 af[4], bfv[4];
#pragma unroll
        for (int i = 0; i < 4; ++i) {
            union { bf16x8 v; unsigned u[4]; } a;
#pragma unroll
            for (int q = 0; q < 4; ++q)
                a.u[q] = pack2(ta[i][2 * q], ta[i][2 * q + 1]);
            af[i] = a.v;
        }
#pragma unroll
        for (int j = 0; j < 4; ++j) {
            union { bf16x8 v; unsigned u[4]; } bv;
#pragma unroll
            for (int q = 0; q < 4; ++q)
                bv.u[q] = pack2(tb[j][2 * q] * mj[2 * q], tb[j][2 * q + 1] * mj[2 * q + 1]);
            bfv[j] = bv.v;
        }
#pragma unroll
        for (int i = 0; i < 4; ++i)
#pragma unroll
            for (int j = 0; j < 4; ++j)
                acc[i][j] = __builtin_amdgcn_mfma_f32_16x16x32_bf16(af[i], bfv[j], acc[i][j], 0, 0, 0);
    }

    float* og = ATOMIC ? (P + ((size_t)g << 14))
                       : (P + ((size_t)(g * NB + b) << 14));
#pragma unroll
    for (int i = 0; i < 4; ++i)
#pragma unroll
        for (int j = 0; j < 4; ++j)
#pragma unroll
            for (int t = 0; t < 4; ++t) {
                const int kk = r0 + 16 * i + hi * 4 + t;   // C row = (lane>>4)*4+reg
                const int dd = c0 + 16 * j + lo;           // C col = lane&15
                if (ATOMIC) atomicAdd(og + kk * ND + dd, acc[i][j][t]);
                else        og[kk * ND + dd] = acc[i][j][t];
            }
}

// ---------------------------------------------------------------------------
// Kernel 2: reduce NPART partials + apply exp(-lambda*t), write Yt[g][d][k]
// (transposed so GEMM2 B-fragments are k-contiguous). Reads coalesced over d;
// 2B scattered writes land in the L2-resident 256KB Yt region.
// ---------------------------------------------------------------------------
template<int NPART>
__global__ __launch_bounds__(256) void k_red(const float* __restrict__ P,
                                             const float* __restrict__ evals,
                                             const float* __restrict__ dt,
                                             unsigned short* __restrict__ Yt) {
    const int gid = blockIdx.x * 256 + threadIdx.x;   // 0 .. 8*128*128-1
    const int g = gid >> 14, k = (gid >> 7) & 127, d = gid & 127;
    const float* p = P + (((size_t)g * NPART) << 14) + (k << 7) + d;
    float s = 0.f;
#pragma unroll 4
    for (int b = 0; b < NPART; ++b) s += p[(size_t)b << 14];
    const float t = fmaxf(dt[d], 1e-8f);
    s *= __expf(-evals[g * NK + k] * t);
    Yt[((size_t)g << 14) + (d << 7) + k] = bf16r(s);
}

// ---------------------------------------------------------------------------
// Kernel 3: out[v,d] = sum_k E[v,k] * Yt[g][d][k]
// Barrier-free, no LDS. Wave = 32 rows x 128 cols; block = 128 rows.
// A-frags: 2x f32x4 per (i,ks) straight from E (each E row read by exactly
// one wave, fully covered across hi/ks). B-frags: 16B bf16x8 from Yt,
// identical addresses across the 4 waves -> L1 broadcast.
// ---------------------------------------------------------------------------
__global__ __launch_bounds__(256, 2) void k_out(const float* __restrict__ evecs,
                                                const unsigned short* __restrict__ Yt,
                                                float* __restrict__ out) {
    const int g    = blockIdx.y;
    const int v0   = blockIdx.x * 128;
    const int rows = (VG - v0 < 128) ? (VG - v0) : 128;

    const float* eg = evecs + (size_t)g * VG * NK;
    float*       og = out   + (size_t)g * VG * ND;
    const unsigned short* yg = Yt + ((size_t)g << 14);

    const int tid = threadIdx.x;
    const int l  = tid & 63, w = tid >> 6;
    const int lo = l & 15, hi = l >> 4;
    const int vr = w * 32;                   // wave's row offset within tile

    f32x4 acc[2][8] = {};

#pragma unroll 2
    for (int ks = 0; ks < 4; ++ks) {
        const int k0 = ks * 32 + hi * 8;

        bf16x8 bfv[8], af[2];
#pragma unroll
        for (int j = 0; j < 8; ++j)
            bfv[j] = *(const bf16x8*)(yg + (size_t)(16 * j + lo) * NK + k0);
#pragma unroll
        for (int i = 0; i < 2; ++i) {
            int rr = vr + 16 * i + lo;
            rr = (rr < rows) ? rr : (rows - 1);          // clamp tail OOB reads
            const f32x4 e0 = *(const f32x4*)(eg + (size_t)(v0 + rr) * NK + k0);
            const f32x4 e1 = *(const f32x4*)(eg + (size_t)(v0 + rr) * NK + k0 + 4);
            union { bf16x8 v; unsigned u[4]; } a;
            a.u[0] = pack2(e0.x, e0.y); a.u[1] = pack2(e0.z, e0.w);
            a.u[2] = pack2(e1.x, e1.y); a.u[3] = pack2(e1.z, e1.w);
            af[i] = a.v;
        }
#pragma unroll
        for (int i = 0; i < 2; ++i)
#pragma unroll
            for (int j = 0; j < 8; ++j)
                acc[i][j] = __builtin_amdgcn_mfma_f32_16x16x32_bf16(af[i], bfv[j], acc[i][j], 0, 0, 0);
    }

#pragma unroll
    for (int i = 0; i < 2; ++i)
#pragma unroll
        for (int t = 0; t < 4; ++t) {
            const int rr = vr + 16 * i + hi * 4 + t;
            if (rr < rows) {
#pragma unroll
                for (int j = 0; j < 8; ++j)
                    og[(size_t)(v0 + rr) * ND + 16 * j + lo] = acc[i][j][t];
            }
        }
}

extern "C" void kernel_launch(void* const* d_in, const int* in_sizes, int n_in,
                              void* d_out, int out_size, void* d_ws, size_t ws_size,
                              hipStream_t stream) {
    const float* x     = (const float*)d_in[0];
    const float* mass  = (const float*)d_in[1];
    const float* evals = (const float*)d_in[2];
    const float* evecs = (const float*)d_in[3];
    const float* dt    = (const float*)d_in[4];
    float* out = (float*)d_out;

    const size_t pelems = (size_t)BGR * NB * NK * ND;          // 33 MB of partials
    const size_t need   = pelems * 4 + (size_t)BGR * NK * ND * 2;

    if (ws_size >= need) {
        // partials + reduce path (no atomics, no memset)
        float*          P  = (float*)d_ws;
        unsigned short* Yt = (unsigned short*)((char*)d_ws + pelems * 4);
        k_spec<0><<<dim3(NB, BGR), 256, 0, stream>>>(x, mass, evecs, P);
        k_red<NB><<<(BGR * NK * ND) / 256, 256, 0, stream>>>(P, evals, dt, Yt);
        k_out<<<dim3((VG + 127) / 128, BGR), 256, 0, stream>>>(evecs, Yt, out);
    } else {
        // fallback: atomic accumulation into one 512KB slab
        float*          P  = (float*)d_ws;
        unsigned short* Yt = (unsigned short*)((char*)d_ws + (size_t)BGR * NK * ND * 4);
        hipMemsetAsync(P, 0, (size_t)BGR * NK * ND * sizeof(float), stream);
        k_spec<1><<<dim3(NB, BGR), 256, 0, stream>>>(x, mass, evecs, P);
        k_red<1><<<(BGR * NK * ND) / 256, 256, 0, stream>>>(P, evals, dt, Yt);
        k_out<<<dim3((VG + 127) / 128, BGR), 256, 0, stream>>>(evecs, Yt, out);
    }
}